// Round 5
// baseline (38.290 us; speedup 1.0000x reference)
//
#include <hip/hip_runtime.h>

#define N_EL 30
#define LAMBDA_COORD 5.0f
#define LAMBDA_NOOBJ 0.5f
#define CPB 64                     // cells per block (1 wave, 1 cell/lane)
#define FLOATS_PER (CPB * N_EL)    // 1920 floats per tensor per block
#define VEC4_PER (FLOATS_PER / 4)  // 480 float4 per tensor per block

typedef const __attribute__((address_space(1))) void gas_void;
typedef __attribute__((address_space(3))) void las_void;

__device__ __forceinline__ float iou_fn(const float* p, const float* t) {
    float ltx = fmaxf(p[0], t[0]);
    float lty = fmaxf(p[1], t[1]);
    float rbx = fminf(p[2], t[2]);
    float rby = fminf(p[3], t[3]);
    float w = fmaxf(rbx - ltx, 0.0f);
    float h = fmaxf(rby - lty, 0.0f);
    float inter = w * h;
    float a1 = (p[2] - p[0]) * (p[3] - p[1]);
    float a2 = (t[2] - t[0]) * (t[3] - t[1]);
    return inter / (a1 + a2 - inter + 1e-10f);
}

// 1-wave block: 15.4 KB LDS -> 10 blocks/CU co-resident; each block is an
// independent stage->compute pipeline, so the CU always has loads in flight.
__global__ __launch_bounds__(64) void yolo_loss_main(
    const float* __restrict__ pred,
    const float* __restrict__ tgt,
    float* __restrict__ partials)
{
    __shared__ float sp[FLOATS_PER];
    __shared__ float st[FLOATS_PER];

    const int lane = threadIdx.x;          // 0..63, single wave

    const float4* Pg = reinterpret_cast<const float4*>(pred) + (size_t)blockIdx.x * VEC4_PER;
    const float4* Tg = reinterpret_cast<const float4*>(tgt)  + (size_t)blockIdx.x * VEC4_PER;
    float4* sp4 = reinterpret_cast<float4*>(sp);
    float4* st4 = reinterpret_cast<float4*>(st);

    // 7 full rounds of 64 float4 per tensor via direct global->LDS DMA
    #pragma unroll
    for (int r = 0; r < 7; ++r) {
        int i = r * 64 + lane;
        __builtin_amdgcn_global_load_lds((gas_void*)(Pg + i), (las_void*)(sp4 + r * 64), 16, 0, 0);
        __builtin_amdgcn_global_load_lds((gas_void*)(Tg + i), (las_void*)(st4 + r * 64), 16, 0, 0);
    }
    // tail: 32 float4 per tensor, register-staged (half-wave each tensor)
    {
        int i = 7 * 64 + (lane & 31);
        if (lane < 32) sp4[i] = Pg[i];
        else           st4[i] = Tg[i];
    }
    __syncthreads();   // drains vmcnt/lgkmcnt; trivial barrier for 1 wave

    // ---- per-cell compute from LDS (cell = lane) ----
    float p[N_EL], t[N_EL];
    const float2* lp = reinterpret_cast<const float2*>(sp + lane * N_EL);
    const float2* lt = reinterpret_cast<const float2*>(st + lane * N_EL);
    #pragma unroll
    for (int i = 0; i < 15; ++i) {
        float2 a = lp[i]; p[2*i] = a.x; p[2*i+1] = a.y;
        float2 b = lt[i]; t[2*i] = b.x; t[2*i+1] = b.y;
    }

    bool coord = (t[5] > 0.0f);
    bool noobj = (t[5] == 0.0f);

    float d4 = p[4] - t[4];
    float d9 = p[9] - t[9];
    float noobj_loss = noobj ? (d4 * d4 + d9 * d9) : 0.0f;

    float cls = 0.0f;
    #pragma unroll
    for (int k = 10; k < 30; ++k) { float d = p[k] - t[k]; cls += d * d; }
    cls = coord ? cls : 0.0f;

    float iou00 = iou_fn(p,     t);
    float iou01 = iou_fn(p,     t + 5);
    float iou10 = iou_fn(p + 5, t);
    float iou11 = iou_fn(p + 5, t + 5);
    bool m0 = (iou10 > iou00);   // pred box chosen for target 0 (tie -> 0)
    bool m1 = (iou11 > iou01);
    bool r0 = coord && ((!m0) || (!m1));
    bool r1 = coord && (m0 || m1);

    float contain = (r0 ? d4 * d4 : 0.0f) + (r1 ? d9 * d9 : 0.0f);

    float loc = 0.0f;
    #pragma unroll
    for (int k = 0; k < 4; ++k) { float d = p[k] - t[k]; loc += r0 ? d * d : 0.0f; }
    #pragma unroll
    for (int k = 5; k < 9; ++k) { float d = p[k] - t[k]; loc += r1 ? d * d : 0.0f; }

    float total = LAMBDA_COORD * loc + contain + LAMBDA_NOOBJ * noobj_loss + cls;

    // ---- single-wave reduction, plain store (no atomic) ----
    #pragma unroll
    for (int off = 32; off > 0; off >>= 1)
        total += __shfl_down(total, off, 64);
    if (lane == 0) partials[blockIdx.x] = total;
}

__global__ __launch_bounds__(256) void yolo_loss_final(
    const float* __restrict__ partials,
    float* __restrict__ out,
    int n4)   // number of float4 elements
{
    const int tid = threadIdx.x;
    const float4* p4 = reinterpret_cast<const float4*>(partials);
    float s = 0.0f;
    for (int i = tid; i < n4; i += 256) {
        float4 v = p4[i];
        s += v.x + v.y + v.z + v.w;
    }

    #pragma unroll
    for (int off = 32; off > 0; off >>= 1)
        s += __shfl_down(s, off, 64);

    __shared__ float ws[4];
    int lane = tid & 63;
    int wid  = tid >> 6;
    if (lane == 0) ws[wid] = s;
    __syncthreads();
    if (tid == 0) out[0] = ws[0] + ws[1] + ws[2] + ws[3];
}

extern "C" void kernel_launch(void* const* d_in, const int* in_sizes, int n_in,
                              void* d_out, int out_size, void* d_ws, size_t ws_size,
                              hipStream_t stream) {
    const float* pred = (const float*)d_in[0];
    const float* tgt  = (const float*)d_in[1];
    float* out = (float*)d_out;
    float* partials = (float*)d_ws;
    int n_cells = in_sizes[0] / N_EL;          // 802816 = 64 * 12544
    int grid = n_cells / CPB;                  // 12544, exact

    yolo_loss_main<<<grid, 64, 0, stream>>>(pred, tgt, partials);
    yolo_loss_final<<<1, 256, 0, stream>>>(partials, out, grid / 4);  // 12544 % 4 == 0
}

// Round 6
// 37.485 us; speedup vs baseline: 1.0215x; 1.0215x over previous
//
#include <hip/hip_runtime.h>

#define N_EL 30
#define LAMBDA_COORD 5.0f
#define LAMBDA_NOOBJ 0.5f
#define CPB 128                    // cells per block (1 wave, 2 cells/lane)
#define FLOATS_PER (CPB * N_EL)    // 3840 floats per tensor per block
#define VEC4_PER (FLOATS_PER / 4)  // 960 float4 per tensor per block -> 15 rounds of 64

typedef const __attribute__((address_space(1))) void gas_void;
typedef __attribute__((address_space(3))) void las_void;

__device__ __forceinline__ float iou_fn(const float* p, const float* t) {
    float ltx = fmaxf(p[0], t[0]);
    float lty = fmaxf(p[1], t[1]);
    float rbx = fminf(p[2], t[2]);
    float rby = fminf(p[3], t[3]);
    float w = fmaxf(rbx - ltx, 0.0f);
    float h = fmaxf(rby - lty, 0.0f);
    float inter = w * h;
    float a1 = (p[2] - p[0]) * (p[3] - p[1]);
    float a2 = (t[2] - t[0]) * (t[3] - t[1]);
    return inter / (a1 + a2 - inter + 1e-10f);
}

__device__ __forceinline__ float cell_loss(const float* __restrict__ spc,
                                           const float* __restrict__ stc) {
    float p[N_EL], t[N_EL];
    const float2* lp = reinterpret_cast<const float2*>(spc);
    const float2* lt = reinterpret_cast<const float2*>(stc);
    #pragma unroll
    for (int i = 0; i < 15; ++i) {
        float2 a = lp[i]; p[2*i] = a.x; p[2*i+1] = a.y;
        float2 b = lt[i]; t[2*i] = b.x; t[2*i+1] = b.y;
    }

    bool coord = (t[5] > 0.0f);
    bool noobj = (t[5] == 0.0f);

    float d4 = p[4] - t[4];
    float d9 = p[9] - t[9];
    float noobj_loss = noobj ? (d4 * d4 + d9 * d9) : 0.0f;

    float cls = 0.0f;
    #pragma unroll
    for (int k = 10; k < 30; ++k) { float d = p[k] - t[k]; cls += d * d; }
    cls = coord ? cls : 0.0f;

    float iou00 = iou_fn(p,     t);
    float iou01 = iou_fn(p,     t + 5);
    float iou10 = iou_fn(p + 5, t);
    float iou11 = iou_fn(p + 5, t + 5);
    bool m0 = (iou10 > iou00);   // pred box chosen for target 0 (tie -> 0)
    bool m1 = (iou11 > iou01);
    bool r0 = coord && ((!m0) || (!m1));
    bool r1 = coord && (m0 || m1);

    float contain = (r0 ? d4 * d4 : 0.0f) + (r1 ? d9 * d9 : 0.0f);

    float loc = 0.0f;
    #pragma unroll
    for (int k = 0; k < 4; ++k) { float d = p[k] - t[k]; loc += r0 ? d * d : 0.0f; }
    #pragma unroll
    for (int k = 5; k < 9; ++k) { float d = p[k] - t[k]; loc += r1 ? d * d : 0.0f; }

    return LAMBDA_COORD * loc + contain + LAMBDA_NOOBJ * noobj_loss + cls;
}

// 1-wave block, CPB=128: exactly 15 global_load_lds rounds per tensor (no tail),
// 30.7 KB LDS -> 5 blocks/CU; 2 cells per lane in compute.
__global__ __launch_bounds__(64) void yolo_loss_main(
    const float* __restrict__ pred,
    const float* __restrict__ tgt,
    float* __restrict__ partials)
{
    __shared__ float sp[FLOATS_PER];
    __shared__ float st[FLOATS_PER];

    const int lane = threadIdx.x;          // 0..63, single wave

    const float4* Pg = reinterpret_cast<const float4*>(pred) + (size_t)blockIdx.x * VEC4_PER;
    const float4* Tg = reinterpret_cast<const float4*>(tgt)  + (size_t)blockIdx.x * VEC4_PER;
    float4* sp4 = reinterpret_cast<float4*>(sp);
    float4* st4 = reinterpret_cast<float4*>(st);

    #pragma unroll
    for (int r = 0; r < 15; ++r) {         // clean rounds, linear LDS dest
        int i = r * 64 + lane;
        __builtin_amdgcn_global_load_lds((gas_void*)(Pg + i), (las_void*)(sp4 + r * 64), 16, 0, 0);
        __builtin_amdgcn_global_load_lds((gas_void*)(Tg + i), (las_void*)(st4 + r * 64), 16, 0, 0);
    }
    __syncthreads();   // vmcnt(0) drain + barrier (1 wave, cheap)

    float total = cell_loss(sp + lane * N_EL,        st + lane * N_EL)
                + cell_loss(sp + (lane + 64) * N_EL, st + (lane + 64) * N_EL);

    // ---- single-wave reduction, plain store (no atomic) ----
    #pragma unroll
    for (int off = 32; off > 0; off >>= 1)
        total += __shfl_down(total, off, 64);
    if (lane == 0) partials[blockIdx.x] = total;
}

__global__ __launch_bounds__(256) void yolo_loss_final(
    const float* __restrict__ partials,
    float* __restrict__ out,
    int n4)   // number of float4 elements
{
    const int tid = threadIdx.x;
    const float4* p4 = reinterpret_cast<const float4*>(partials);
    float s = 0.0f;
    for (int i = tid; i < n4; i += 256) {
        float4 v = p4[i];
        s += v.x + v.y + v.z + v.w;
    }

    #pragma unroll
    for (int off = 32; off > 0; off >>= 1)
        s += __shfl_down(s, off, 64);

    __shared__ float ws[4];
    int lane = tid & 63;
    int wid  = tid >> 6;
    if (lane == 0) ws[wid] = s;
    __syncthreads();
    if (tid == 0) out[0] = ws[0] + ws[1] + ws[2] + ws[3];
}

extern "C" void kernel_launch(void* const* d_in, const int* in_sizes, int n_in,
                              void* d_out, int out_size, void* d_ws, size_t ws_size,
                              hipStream_t stream) {
    const float* pred = (const float*)d_in[0];
    const float* tgt  = (const float*)d_in[1];
    float* out = (float*)d_out;
    float* partials = (float*)d_ws;
    int n_cells = in_sizes[0] / N_EL;          // 802816 = 128 * 6272
    int grid = n_cells / CPB;                  // 6272, exact

    yolo_loss_main<<<grid, 64, 0, stream>>>(pred, tgt, partials);
    yolo_loss_final<<<1, 256, 0, stream>>>(partials, out, grid / 4);  // 6272 % 4 == 0
}